// Round 10
// baseline (426.255 us; speedup 1.0000x reference)
//
#include <hip/hip_runtime.h>
#include <hip/hip_fp16.h>

#define F 64
#define CHUNK 1024   // edges per block in binning kernels (256 thr x 4)

typedef int v4i __attribute__((ext_vector_type(4)));

__device__ __forceinline__ float rlane(float v, int l) {
    return __uint_as_float(__builtin_amdgcn_readlane(__float_as_uint(v), l));
}

// ============ fused degree count + per-chunk per-segment histogram ============
__global__ __launch_bounds__(256) void k_blkcnt(const int* __restrict__ dst,
                                                int* count, int* __restrict__ blkcnt,
                                                int E, int step, int NB) {
    __shared__ int lcnt[8];
    int b = blockIdx.x, t = threadIdx.x;
    if (t < 8) lcnt[t] = 0;
    __syncthreads();
    int e0 = b * CHUNK;
#pragma unroll
    for (int k = 0; k < 4; ++k) {
        int e = e0 + t + k * 256;
        if (e < E) {
            int d = __builtin_nontemporal_load(&dst[e]);
            atomicAdd(&count[d], 1);
            atomicAdd(&lcnt[d / step], 1);
        }
    }
    __syncthreads();
    if (t < 8) blkcnt[t * NB + b] = lcnt[t];   // seg-major layout
}

// ============ scan of pad-4 counts -> row_start; also dis ============
__global__ void k_reduce(const int* __restrict__ c, int* __restrict__ bsum, int n) {
    __shared__ int s[256];
    int t = threadIdx.x;
    int i = blockIdx.x * 256 + t;
    s[t] = (i < n) ? ((c[i] + 3) & ~3) : 0;
    __syncthreads();
    for (int off = 128; off > 0; off >>= 1) {
        if (t < off) s[t] += s[t + off];
        __syncthreads();
    }
    if (t == 0) bsum[blockIdx.x] = s[0];
}

__global__ void k_scan_bsum(int* bs, int nb) {
    __shared__ int s[512];
    int t = threadIdx.x;
    int v = (t < nb) ? bs[t] : 0;
    s[t] = v;
    __syncthreads();
    for (int off = 1; off < 512; off <<= 1) {
        int x = (t >= off) ? s[t - off] : 0;
        __syncthreads();
        s[t] += x;
        __syncthreads();
    }
    if (t < nb) bs[t] = s[t] - v;  // exclusive
}

// scan + row_start + cursor + dis + CSR pad slots (normal stores — r9 showed
// nt scattered stores INCREASE writeback on gfx950)
__global__ void k_scan_write(const int* __restrict__ c, const int* __restrict__ boff,
                             int* __restrict__ row_start, int* __restrict__ cursor,
                             float* __restrict__ dis, int* __restrict__ csr, int n) {
    __shared__ int s[256];
    int t = threadIdx.x;
    int i = blockIdx.x * 256 + t;
    int cv = (i < n) ? c[i] : 0;
    int v = (cv + 3) & ~3;
    if (i >= n) v = 0;
    s[t] = v;
    __syncthreads();
    for (int off = 1; off < 256; off <<= 1) {
        int x = (t >= off) ? s[t - off] : 0;
        __syncthreads();
        s[t] += x;
        __syncthreads();
    }
    if (i <= n) {
        int excl = s[t] - v + boff[blockIdx.x];
        row_start[i] = excl;
        if (i < n) {
            cursor[i] = excl;
            dis[i] = rsqrtf((float)(cv + 1));
            for (int p = excl + cv; p < excl + v; ++p) csr[p] = n;
        }
    }
}

// ============ per-segment exclusive scan over chunk counts ============
// 8 blocks; block seg scans blkcnt[seg][0..NB) -> blkoff, total -> segtot[seg]
__global__ __launch_bounds__(256) void k_segscan(const int* __restrict__ blkcnt,
                                                 int* __restrict__ blkoff,
                                                 int* __restrict__ segtot, int NB) {
    __shared__ int s[256];
    __shared__ int running;
    int seg = blockIdx.x;
    int t = threadIdx.x;
    if (t == 0) running = 0;
    __syncthreads();
    for (int base = 0; base < NB; base += 256) {
        int i = base + t;
        int v = (i < NB) ? blkcnt[seg * NB + i] : 0;
        s[t] = v;
        __syncthreads();
        for (int off = 1; off < 256; off <<= 1) {
            int x = (t >= off) ? s[t - off] : 0;
            __syncthreads();
            s[t] += x;
            __syncthreads();
        }
        int rbase = running;
        if (i < NB) blkoff[seg * NB + i] = rbase + s[t] - v;
        int ctot = s[255];
        __syncthreads();
        if (t == 0) running = rbase + ctot;
        __syncthreads();
    }
    if (t == 0) segtot[seg] = running;
}

// ============ stage edges into per-segment contiguous record regions ============
// LDS-binned by dst segment; global writes are coalesced runs. No claim atomics.
__global__ __launch_bounds__(256) void k_stage(const int* __restrict__ src,
                                               const int* __restrict__ dst,
                                               const int* __restrict__ blkoff,
                                               const int* __restrict__ segtot,
                                               uint2* __restrict__ stage,
                                               int E, int step, int NB) {
    __shared__ int lcnt[8];
    __shared__ int lbase[9];
    __shared__ int sbase[8];
    __shared__ uint2 rec[CHUNK];
    int b = blockIdx.x, t = threadIdx.x;
    if (t < 8) lcnt[t] = 0;
    __syncthreads();
    int e0 = b * CHUNK;
    int myseg[4], myrank[4];
    uint2 myrec[4];
#pragma unroll
    for (int k = 0; k < 4; ++k) {
        int e = e0 + t + k * 256;
        myseg[k] = -1;
        if (e < E) {
            int d = __builtin_nontemporal_load(&dst[e]);
            int sv = __builtin_nontemporal_load(&src[e]);
            int sg = d / step;
            myseg[k] = sg;
            myrank[k] = atomicAdd(&lcnt[sg], 1);
            myrec[k] = make_uint2((unsigned)d, (unsigned)sv);
        }
    }
    __syncthreads();
    if (t == 0) {
        int acc = 0;
#pragma unroll
        for (int i2 = 0; i2 < 8; ++i2) { lbase[i2] = acc; acc += lcnt[i2]; }
        lbase[8] = acc;
    }
    if (t < 8) {
        int acc2 = 0;
        for (int i2 = 0; i2 < t; ++i2) acc2 += segtot[i2];
        sbase[t] = acc2 + blkoff[t * NB + b];
    }
    __syncthreads();
#pragma unroll
    for (int k = 0; k < 4; ++k)
        if (myseg[k] >= 0) rec[lbase[myseg[k]] + myrank[k]] = myrec[k];
    __syncthreads();
    int tot = lbase[8];
    for (int j = t; j < tot; j += 256) {
        int sg = 0;
#pragma unroll
        for (int i2 = 1; i2 < 8; ++i2) sg += (j >= lbase[i2]);
        stage[sbase[sg] + (j - lbase[sg])] = rec[j];
    }
}

// ============ per-segment scatter fill: one XCD per segment (heuristic) ============
// Block handles seg = blockIdx&7. Working set per XCD: seg's record stream
// (~1.6 MB, read once) + seg's csr window (~1.5 MB) + cursors (~50 KB) < 4 MB L2.
__global__ __launch_bounds__(256) void k_fillseg(const uint2* __restrict__ stage,
                                                 const int* __restrict__ segtot,
                                                 int* cursor, int* __restrict__ csr,
                                                 int nsegb) {
    __shared__ int base_s, tot_s;
    int sg = blockIdx.x & 7;
    int bs = blockIdx.x >> 3;
    if (threadIdx.x == 0) {
        int acc = 0;
        for (int i = 0; i < sg; ++i) acc += segtot[i];
        base_s = acc;
        tot_s = segtot[sg];
    }
    __syncthreads();
    int base = base_s, tot = tot_s;
    for (int i = bs * 256 + threadIdx.x; i < tot; i += nsegb * 256) {
        uint2 r = stage[base + i];
        int p = atomicAdd(&cursor[(int)r.x], 1);
        csr[p] = (int)r.y;
    }
}

// ============ hs0 = fp16(dis * x); zero row n of BOTH buffers ============
__global__ void k_prep(const float* __restrict__ x, const float* __restrict__ dis,
                       __half* __restrict__ hs, __half* __restrict__ hs2, int n) {
    int i = blockIdx.x * blockDim.x + threadIdx.x;
    int tot = (n + 1) * F;
    if (i < tot) {
        int row = i >> 6;
        hs[i] = __float2half((row < n) ? dis[row] * x[i] : 0.0f);
    } else if (i < tot + F) {
        hs2[(size_t)n * F + (i - tot)] = __float2half(0.0f);
    }
}

__device__ __forceinline__ void h4acc(uint2 u, float* t) {
    float2 fa = __half22float2(*(__half2*)&u.x);
    float2 fb = __half22float2(*(__half2*)&u.y);
    t[0] += fa.x; t[1] += fa.y; t[2] += fb.x; t[3] += fb.y;
}

// ============ fused GCN layer: wide-gather, 4 dst rows/wave ============
__global__ __launch_bounds__(256) void k_layer(const __half* __restrict__ hin,
                                               const float* __restrict__ W,
                                               const float* __restrict__ b,
                                               const int* __restrict__ row_start,
                                               const int* __restrict__ csr,
                                               const float* __restrict__ dis,
                                               __half* __restrict__ hout,
                                               int n, int scale_out) {
    __shared__ float Ws[F * F];
    int tid = threadIdx.x;
#pragma unroll
    for (int i = 0; i < 16; ++i) Ws[tid + i * 256] = W[tid + i * 256];
    __syncthreads();
    int lane = tid & 63;
    int g = lane >> 4;
    int sub = lane & 15;
    int r0 = (blockIdx.x * 4 + (tid >> 6)) * 4;
    if (r0 >= n) return;

    int s0 = row_start[r0];
    int s1 = row_start[r0 + 1];
    int s2 = row_start[r0 + 2];
    int s3 = row_start[r0 + 3];
    int s4 = row_start[r0 + 4];

    float a0[4] = {0, 0, 0, 0};
    float a1[4] = {0, 0, 0, 0};
    float a2[4] = {0, 0, 0, 0};
    float a3[4] = {0, 0, 0, 0};

    const v4i* csr4 = (const v4i*)csr;
    const uint2* h2 = (const uint2*)hin;
    int B0 = s0 >> 2, B4 = s4 >> 2;
    for (int bb = B0; bb < B4; bb += 4) {
        int mybb = bb + g;
        bool valid = mybb < B4;
        v4i q = __builtin_nontemporal_load(csr4 + (valid ? mybb : B0));
        if (!valid) { q.x = n; q.y = n; q.z = n; q.w = n; }
        int slot = mybb << 2;
        int r = (slot >= s1) + ((slot >= s2) + (slot >= s3));
        uint2 qa = h2[((size_t)q.x << 4) + sub];
        uint2 qb = h2[((size_t)q.y << 4) + sub];
        uint2 qc = h2[((size_t)q.z << 4) + sub];
        uint2 qd = h2[((size_t)q.w << 4) + sub];
        float t[4] = {0, 0, 0, 0};
        h4acc(qa, t); h4acc(qb, t); h4acc(qc, t); h4acc(qd, t);
        float m0 = (r == 0) ? 1.0f : 0.0f;
        float m1 = (r == 1) ? 1.0f : 0.0f;
        float m2 = (r == 2) ? 1.0f : 0.0f;
        float m3 = (r == 3) ? 1.0f : 0.0f;
#pragma unroll
        for (int m = 0; m < 4; ++m) {
            a0[m] = fmaf(m0, t[m], a0[m]);
            a1[m] = fmaf(m1, t[m], a1[m]);
            a2[m] = fmaf(m2, t[m], a2[m]);
            a3[m] = fmaf(m3, t[m], a3[m]);
        }
    }

#pragma unroll
    for (int m = 0; m < 4; ++m) {
        a0[m] += __shfl_xor(a0[m], 16); a0[m] += __shfl_xor(a0[m], 32);
        a1[m] += __shfl_xor(a1[m], 16); a1[m] += __shfl_xor(a1[m], 32);
        a2[m] += __shfl_xor(a2[m], 16); a2[m] += __shfl_xor(a2[m], 32);
        a3[m] += __shfl_xor(a3[m], 16); a3[m] += __shfl_xor(a3[m], 32);
    }

    {
        uint2 u0 = h2[((size_t)(r0 + 0) << 4) + sub];
        uint2 u1 = h2[((size_t)(r0 + 1) << 4) + sub];
        uint2 u2 = h2[((size_t)(r0 + 2) << 4) + sub];
        uint2 u3 = h2[((size_t)(r0 + 3) << 4) + sub];
        h4acc(u0, a0); h4acc(u1, a1); h4acc(u2, a2); h4acc(u3, a3);
    }
    float d0 = dis[r0 + 0], d1 = dis[r0 + 1], d2 = dis[r0 + 2], d3 = dis[r0 + 3];
#pragma unroll
    for (int m = 0; m < 4; ++m) {
        a0[m] *= d0; a1[m] *= d1; a2[m] *= d2; a3[m] *= d3;
    }

    float bb_ = b[lane];
    float y0 = bb_, y1 = bb_, y2 = bb_, y3 = bb_;
#pragma unroll
    for (int a = 0; a < 16; ++a) {
#pragma unroll
        for (int m = 0; m < 4; ++m) {
            float w = Ws[(((a << 2) + m) << 6) + lane];
            y0 = fmaf(rlane(a0[m], a), w, y0);
            y1 = fmaf(rlane(a1[m], a), w, y1);
            y2 = fmaf(rlane(a2[m], a), w, y2);
            y3 = fmaf(rlane(a3[m], a), w, y3);
        }
    }
    y0 = fmaxf(y0, 0.0f);
    y1 = fmaxf(y1, 0.0f);
    y2 = fmaxf(y2, 0.0f);
    y3 = fmaxf(y3, 0.0f);
    if (scale_out) { y0 *= d0; y1 *= d1; y2 *= d2; y3 *= d3; }
    hout[((size_t)(r0 + 0) << 6) + lane] = __float2half(y0);
    hout[((size_t)(r0 + 1) << 6) + lane] = __float2half(y1);
    hout[((size_t)(r0 + 2) << 6) + lane] = __float2half(y2);
    hout[((size_t)(r0 + 3) << 6) + lane] = __float2half(y3);
}

// ============ final 64->8 linear (fp16 input, fp32 math/out) ============
__global__ __launch_bounds__(256) void k_final(const __half* __restrict__ h,
                                               const float* __restrict__ Wl,
                                               const float* __restrict__ bl,
                                               float* __restrict__ out, int n) {
    __shared__ float Ws[F * 8];
    __shared__ float bs[8];
    int tid = threadIdx.x;
    Ws[tid] = Wl[tid];
    Ws[tid + 256] = Wl[tid + 256];
    if (tid < 8) bs[tid] = bl[tid];
    __syncthreads();
    int idx = blockIdx.x * 256 + tid;
    if (idx >= n * 8) return;
    int row = idx >> 3;
    int o = idx & 7;
    const __half* hr = h + (size_t)row * F;
    float acc = bs[o];
#pragma unroll
    for (int k = 0; k < F; ++k) acc = fmaf(__half2float(hr[k]), Ws[k * 8 + o], acc);
    out[idx] = acc;
}

extern "C" void kernel_launch(void* const* d_in, const int* in_sizes, int n_in,
                              void* d_out, int out_size, void* d_ws, size_t ws_size,
                              hipStream_t stream) {
    const float* x  = (const float*)d_in[0];
    const int*   ei = (const int*)d_in[1];
    const float* W1 = (const float*)d_in[2];
    const float* b1 = (const float*)d_in[3];
    const float* W2 = (const float*)d_in[4];
    const float* b2 = (const float*)d_in[5];
    const float* W3 = (const float*)d_in[6];
    const float* b3 = (const float*)d_in[7];
    const float* Wl = (const float*)d_in[8];
    const float* bl = (const float*)d_in[9];
    float* out = (float*)d_out;

    int n = in_sizes[0] / F;   // 100000 (n % 4 == 0)
    int E = in_sizes[1] / 2;   // 1600000
    const int* src = ei;
    const int* dst = ei + E;

    int np   = (n + 256) & ~255;          // >= n+1, multiple of 256
    int nb   = (np + 255) / 256;          // <=512 for k_scan_bsum
    int cap  = E + 3 * n + 64;            // worst-case pad-4 CSR size
    int step = (n + 7) / 8;               // 12500 nodes per segment
    int NB   = (E + CHUNK - 1) / CHUNK;   // 1563 chunks

    // workspace layout (~48 MB)
    int*    count     = (int*)d_ws;
    int*    row_start = count + np;
    int*    cursor    = row_start + np;
    int*    bsum      = cursor + np;           // 512
    int*    blkcnt    = bsum + 512;            // 8*NB
    int*    blkoff    = blkcnt + 8 * NB;       // 8*NB
    int*    segtot    = blkoff + 8 * NB;       // 8 (pad 16)
    float*  dis       = (float*)(segtot + 16);
    uint2*  stage     = (uint2*)(dis + np);    // E records (8B each), 8B aligned
    int*    csr       = (int*)(stage + E);
    __half* buf1      = (__half*)(csr + ((cap + 3) & ~3));
    __half* buf2      = buf1 + (size_t)(n + 1) * F;

    // ---- degree + per-chunk segment histogram (one pass over dst) ----
    hipMemsetAsync(count, 0, (size_t)np * sizeof(int), stream);
    k_blkcnt<<<NB, 256, 0, stream>>>(dst, count, blkcnt, E, step, NB);

    // ---- row_start/cursor/dis + pad slots ----
    k_reduce<<<nb, 256, 0, stream>>>(count, bsum, n);
    k_scan_bsum<<<1, 512, 0, stream>>>(bsum, nb);
    k_scan_write<<<nb, 256, 0, stream>>>(count, bsum, row_start, cursor, dis, csr, n);

    // ---- segment-binned fill: scan -> stage (coalesced) -> per-XCD scatter ----
    k_segscan<<<8, 256, 0, stream>>>(blkcnt, blkoff, segtot, NB);
    k_stage<<<NB, 256, 0, stream>>>(src, dst, blkoff, segtot, stage, E, step, NB);
    int nsegb = 104;  // blocks per segment; grid 832 = 8*104
    k_fillseg<<<8 * nsegb, 256, 0, stream>>>(stage, segtot, cursor, csr, nsegb);

    // ---- hs0 = fp16(dis*x); zero row n of buf1 AND buf2 ----
    k_prep<<<((n + 1) * F + F + 255) / 256, 256, 0, stream>>>(x, dis, buf1, buf2, n);

    // ---- 3 fused layers, ping-pong ----
    int nb_l = (n / 4 + 3) / 4;
    k_layer<<<nb_l, 256, 0, stream>>>(buf1, W1, b1, row_start, csr, dis, buf2, n, 1);
    k_layer<<<nb_l, 256, 0, stream>>>(buf2, W2, b2, row_start, csr, dis, buf1, n, 1);
    k_layer<<<nb_l, 256, 0, stream>>>(buf1, W3, b3, row_start, csr, dis, buf2, n, 0);

    // ---- final linear ----
    k_final<<<(n * 8 + 255) / 256, 256, 0, stream>>>(buf2, Wl, bl, out, n);
}